// Round 7
// baseline (1293.928 us; speedup 1.0000x reference)
//
#include <hip/hip_runtime.h>

// HeteroGNN forward (SAGE mean-aggr, two relations), MI355X.
//
// Round 7: two-level binned CSR build.
//  Round-6 lesson: atomicExch serializes (175->318us) and WRITE_SIZE stayed
//  250MB. Root cause of the 16x write amplification: a nbr line's 16 entries
//  arrive spread across the whole 16MB edge stream -> dirty eviction per 4B
//  write. Fix = temporal density:
//   - bin_kernel: 64-node buckets, per-bucket atomicAdd cursor, XCD-owned
//     (bucket&7 == blockIdx&7). Cursor-adjacent slots are written by
//     concurrently-resident blocks of one XCD -> lines fill fast -> writes
//     ~= payload (16MB packed 4B entries: neighbor[18b] | node_low6[6b<<18]).
//   - fine_kernel: one block per bucket; entries+off+degrees staged in LDS;
//     scatter into the bucket's ~10KB nbr range (tight window, one block).
//     No global atomics at all.
//  Also: both gathers merged into one launch over the combined node space.
//  transform_v4 (named-VGPR W + readlane broadcast) kept from round 6.

#define EPB 16384   // edges per chunk in partitioned bin/scatter kernels

// ---------------------------------------------------------------------------
// Phase A: single-pass count
// ---------------------------------------------------------------------------
__global__ void count_kernel(const int* __restrict__ src, const int* __restrict__ dst,
                             int* __restrict__ cnt, int Nr, int nE)
{
    int e = blockIdx.x * blockDim.x + threadIdx.x;
    if (e >= nE) return;
    atomicAdd(&cnt[dst[e]], 1);
    atomicAdd(&cnt[Nr + src[e]], 1);
}

#define SCAN_BS 2048   // elements per block in scan (256 thr x 8)

__global__ void scan_block_kernel(const int* __restrict__ cnt, int* __restrict__ off,
                                  int* __restrict__ partial, int N)
{
    __shared__ int sdata[256];
    const int t = threadIdx.x;
    const long long base = (long long)blockIdx.x * SCAN_BS + (long long)t * 8;
    int v[8];
    int s = 0;
    #pragma unroll
    for (int k = 0; k < 8; ++k) {
        long long i = base + k;
        v[k] = (i < N) ? cnt[i] : 0;
        s += v[k];
    }
    sdata[t] = s;
    __syncthreads();
    for (int d = 1; d < 256; d <<= 1) {
        int val = (t >= d) ? sdata[t - d] : 0;
        __syncthreads();
        if (t >= d) sdata[t] += val;
        __syncthreads();
    }
    if (t == 255) partial[blockIdx.x] = sdata[255];
    int run = sdata[t] - s;   // exclusive prefix for this thread's chunk
    #pragma unroll
    for (int k = 0; k < 8; ++k) {
        long long i = base + k;
        if (i < N) off[i] = run;
        run += v[k];
    }
}

__global__ void scan_partials_kernel(int* __restrict__ partial, int nb)
{
    __shared__ int sdata[256];
    const int t = threadIdx.x;
    int v = (t < nb) ? partial[t] : 0;
    sdata[t] = v;
    __syncthreads();
    for (int d = 1; d < 256; d <<= 1) {
        int val = (t >= d) ? sdata[t - d] : 0;
        __syncthreads();
        if (t >= d) sdata[t] += val;
        __syncthreads();
    }
    if (t < nb) partial[t] = sdata[t] - v;   // exclusive
}

__global__ void scan_addback_kernel(int* __restrict__ off, const int* __restrict__ partial,
                                    int N, int total)
{
    long long i = (long long)blockIdx.x * blockDim.x + threadIdx.x;
    if (i < N) off[i] += partial[i / SCAN_BS];
    if (i == 0) off[N] = total;
}

// ---------------------------------------------------------------------------
// bcur[b] = start of bucket b's entry region = off[b*64]
// ---------------------------------------------------------------------------
__global__ void bcur_init_kernel(const int* __restrict__ off, int* __restrict__ bcur,
                                 int B, int NN)
{
    int b = blockIdx.x * blockDim.x + threadIdx.x;
    if (b < B) bcur[b] = off[min(b * 64, NN)];
}

// ---------------------------------------------------------------------------
// Phase A2: bin. Block p=blockIdx&7 owns buckets with (bucket&7)==p.
// Entry = neighbor_value (18b) | (node & 63) << 18. Plain stores; slot from
// per-bucket atomicAdd cursor (cursor-adjacent slots written concurrently
// by one XCD's blocks -> write combining in that L2).
// ---------------------------------------------------------------------------
__global__ void bin_kernel(const int* __restrict__ src, const int* __restrict__ dst,
                           int* __restrict__ bcur, int* __restrict__ entry,
                           int Nr, int nE)
{
    const int p  = blockIdx.x & 7;
    const int c  = blockIdx.x >> 3;
    const int e0 = c * EPB;
    const int e1 = min(e0 + EPB, nE);
    for (int e = e0 + threadIdx.x; e < e1; e += blockDim.x) {
        const int dr = dst[e];
        const int su = src[e];
        const int br = dr >> 6;
        if ((br & 7) == p) {
            int slot = atomicAdd(&bcur[br], 1);
            entry[slot] = su | ((dr & 63) << 18);
        }
        const int nu = Nr + su;
        const int bu = nu >> 6;
        if ((bu & 7) == p) {
            int slot = atomicAdd(&bcur[bu], 1);
            entry[slot] = dr | ((nu & 63) << 18);
        }
    }
}

// ---------------------------------------------------------------------------
// Phase A3: fine scatter within each bucket. One block per bucket; degrees,
// offsets in LDS; LDS atomicSub assigns exact CSR slots; nbr writes hit a
// ~10KB contiguous region in a tight temporal window.
// ---------------------------------------------------------------------------
__global__ void fine_kernel(const int* __restrict__ entry,
                            const int* __restrict__ off,
                            const int* __restrict__ cnt,
                            int* __restrict__ nbr, int NN)
{
    __shared__ int lcnt[64];
    __shared__ int loff[64];
    const int b  = blockIdx.x;
    const int n0 = b * 64;
    const int nNodes = min(64, NN - n0);
    if (threadIdx.x < nNodes) {
        lcnt[threadIdx.x] = cnt[n0 + threadIdx.x];
        loff[threadIdx.x] = off[n0 + threadIdx.x];
    }
    __syncthreads();
    const int ebeg = off[n0];
    const int eend = off[min(n0 + 64, NN)];
    for (int i = ebeg + threadIdx.x; i < eend; i += blockDim.x) {
        const int e   = entry[i];
        const int low = e >> 18;
        const int val = e & 0x3FFFF;
        const int pos = loff[low] + atomicSub(&lcnt[low], 1) - 1;
        nbr[pos] = val;
    }
}

// ---------------------------------------------------------------------------
// Phase B: merged atomic-free gather + mean over the combined node space.
// g < Nr: resource node, neighbors are user ids -> gather from xu.
// g >= Nr: user node, neighbors are resource ids -> gather from xr.
// Output row = d_out + g*64 (agg_r then agg_u, contiguous by construction).
// ---------------------------------------------------------------------------
__device__ __forceinline__ void f4add(float4& a, const float4 v) {
    a.x += v.x; a.y += v.y; a.z += v.z; a.w += v.w;
}

__global__ void gather_mean_all_kernel(const float* __restrict__ xu,
                                       const float* __restrict__ xr,
                                       const int* __restrict__ off,
                                       const int* __restrict__ nbr,
                                       float* __restrict__ out, int Nr, int NN)
{
    const int tid  = blockIdx.x * blockDim.x + threadIdx.x;
    const int g    = tid >> 4;
    if (g >= NN) return;
    const int lane = tid & 15;
    const int c    = lane << 2;
    const float* __restrict__ x = (g < Nr) ? xu : xr;

    const int beg = off[g];
    const int end = off[g + 1];

    float4 a0 = {0,0,0,0}, a1 = {0,0,0,0}, a2 = {0,0,0,0}, a3 = {0,0,0,0};
    int j = beg;
    for (; j + 4 <= end; j += 4) {
        const int s0 = nbr[j], s1 = nbr[j+1], s2 = nbr[j+2], s3 = nbr[j+3];
        f4add(a0, *reinterpret_cast<const float4*>(x + ((long long)s0 << 6) + c));
        f4add(a1, *reinterpret_cast<const float4*>(x + ((long long)s1 << 6) + c));
        f4add(a2, *reinterpret_cast<const float4*>(x + ((long long)s2 << 6) + c));
        f4add(a3, *reinterpret_cast<const float4*>(x + ((long long)s3 << 6) + c));
    }
    for (; j < end; ++j) {
        f4add(a0, *reinterpret_cast<const float4*>(x + ((long long)nbr[j] << 6) + c));
    }
    f4add(a0, a1); f4add(a2, a3); f4add(a0, a2);

    const float inv = 1.0f / (float)max(end - beg, 1);
    float4 r; r.x = a0.x * inv; r.y = a0.y * inv; r.z = a0.z * inv; r.w = a0.w * inv;
    *reinterpret_cast<float4*>(out + ((long long)g << 6) + c) = r;
}

// ---------------------------------------------------------------------------
// Phase C (v4, unchanged from round 6): lane = output feature h and row
// element d; W in 128 named float4 VGPRs; readlane broadcasts row elements
// as SGPR operands to v_fmac. In-place safe.
// ---------------------------------------------------------------------------
__device__ __forceinline__ float rlane(float v, int l) {
    return __int_as_float(__builtin_amdgcn_readlane(__float_as_int(v), l));
}

#define LWV(nm, W, i) \
    float4 nm; nm.x = W[(4*(i)+0)*64 + lane]; nm.y = W[(4*(i)+1)*64 + lane]; \
    nm.z = W[(4*(i)+2)*64 + lane]; nm.w = W[(4*(i)+3)*64 + lane];

#define TSTEP(i, acc) { \
    acc = fmaf(rlane(va, 4*(i)+0), wl##i.x, acc); \
    acc = fmaf(rlane(va, 4*(i)+1), wl##i.y, acc); \
    acc = fmaf(rlane(va, 4*(i)+2), wl##i.z, acc); \
    acc = fmaf(rlane(va, 4*(i)+3), wl##i.w, acc); \
    acc = fmaf(rlane(vx, 4*(i)+0), wr##i.x, acc); \
    acc = fmaf(rlane(vx, 4*(i)+1), wr##i.y, acc); \
    acc = fmaf(rlane(vx, 4*(i)+2), wr##i.z, acc); \
    acc = fmaf(rlane(vx, 4*(i)+3), wr##i.w, acc); }

__global__ __launch_bounds__(256, 3)
void transform_v4_kernel(const float* __restrict__ agg,
                         const float* __restrict__ xroot,
                         const float* __restrict__ Wl,
                         const float* __restrict__ bl,
                         const float* __restrict__ Wr,
                         float* __restrict__ out, int N)
{
    const int lane = threadIdx.x & 63;
    const int wid  = (blockIdx.x * blockDim.x + threadIdx.x) >> 6;
    const int nw   = (gridDim.x * blockDim.x) >> 6;

    LWV(wl0,  Wl, 0)  LWV(wl1,  Wl, 1)  LWV(wl2,  Wl, 2)  LWV(wl3,  Wl, 3)
    LWV(wl4,  Wl, 4)  LWV(wl5,  Wl, 5)  LWV(wl6,  Wl, 6)  LWV(wl7,  Wl, 7)
    LWV(wl8,  Wl, 8)  LWV(wl9,  Wl, 9)  LWV(wl10, Wl, 10) LWV(wl11, Wl, 11)
    LWV(wl12, Wl, 12) LWV(wl13, Wl, 13) LWV(wl14, Wl, 14) LWV(wl15, Wl, 15)
    LWV(wr0,  Wr, 0)  LWV(wr1,  Wr, 1)  LWV(wr2,  Wr, 2)  LWV(wr3,  Wr, 3)
    LWV(wr4,  Wr, 4)  LWV(wr5,  Wr, 5)  LWV(wr6,  Wr, 6)  LWV(wr7,  Wr, 7)
    LWV(wr8,  Wr, 8)  LWV(wr9,  Wr, 9)  LWV(wr10, Wr, 10) LWV(wr11, Wr, 11)
    LWV(wr12, Wr, 12) LWV(wr13, Wr, 13) LWV(wr14, Wr, 14) LWV(wr15, Wr, 15)
    const float bias = bl[lane];

    for (int r = wid; r < N; r += nw) {
        const long long base = (long long)r << 6;
        const float va = agg[base + lane];     // coalesced; lane = element d
        const float vx = xroot[base + lane];
        float acc0 = bias, acc1 = 0.f, acc2 = 0.f, acc3 = 0.f;
        TSTEP(0,  acc0) TSTEP(1,  acc1) TSTEP(2,  acc2) TSTEP(3,  acc3)
        TSTEP(4,  acc0) TSTEP(5,  acc1) TSTEP(6,  acc2) TSTEP(7,  acc3)
        TSTEP(8,  acc0) TSTEP(9,  acc1) TSTEP(10, acc2) TSTEP(11, acc3)
        TSTEP(12, acc0) TSTEP(13, acc1) TSTEP(14, acc2) TSTEP(15, acc3)
        const float acc = (acc0 + acc1) + (acc2 + acc3);
        out[base + lane] = fmaxf(acc, 0.0f);   // lane = output feature h
    }
}

// ---------------------------------------------------------------------------
// Fallback A: round-5 partitioned scatter (plain stores — NOT atomicExch).
// ---------------------------------------------------------------------------
__global__ void scatter_part_kernel(const int* __restrict__ src, const int* __restrict__ dst,
                                    const int* __restrict__ off, int* __restrict__ cnt,
                                    int* __restrict__ nbr, int Nr, int nE,
                                    float invR, float invU)
{
    const int p  = blockIdx.x & 7;
    const int c  = blockIdx.x >> 3;
    const int e0 = c * EPB;
    const int e1 = min(e0 + EPB, nE);
    for (int e = e0 + threadIdx.x; e < e1; e += blockDim.x) {
        const int dr = dst[e];
        const int su = src[e];
        if (min(7, (int)(dr * invR)) == p) {
            int pos = off[dr] + atomicSub(&cnt[dr], 1) - 1;
            nbr[pos] = su;
        }
        if (min(7, (int)(su * invU)) == p) {
            int pos = off[Nr + su] + atomicSub(&cnt[Nr + su], 1) - 1;
            nbr[pos] = dr;
        }
    }
}

// ---------------------------------------------------------------------------
// Fallback B (round-1) kernels, used only if ws_size is tiny.
// ---------------------------------------------------------------------------
__global__ void edge_scatter_kernel(
    const float* __restrict__ xu, const float* __restrict__ xr,
    const int* __restrict__ src, const int* __restrict__ dst,
    float* __restrict__ agg_r, float* __restrict__ agg_u,
    float* __restrict__ deg_r, float* __restrict__ deg_u,
    int nE)
{
    int tid  = blockIdx.x * blockDim.x + threadIdx.x;
    int e    = tid >> 4;
    if (e >= nE) return;
    int lane = tid & 15;
    int su = src[e];
    int dr = dst[e];
    if (lane == 0) {
        atomicAdd(&deg_r[dr], 1.0f);
        atomicAdd(&deg_u[su], 1.0f);
    }
    const float4 a = *reinterpret_cast<const float4*>(xu + ((long long)su << 6) + (lane << 2));
    const float4 b = *reinterpret_cast<const float4*>(xr + ((long long)dr << 6) + (lane << 2));
    float* pr = agg_r + ((long long)dr << 6) + (lane << 2);
    float* pu = agg_u + ((long long)su << 6) + (lane << 2);
    atomicAdd(pr + 0, a.x); atomicAdd(pr + 1, a.y);
    atomicAdd(pr + 2, a.z); atomicAdd(pr + 3, a.w);
    atomicAdd(pu + 0, b.x); atomicAdd(pu + 1, b.y);
    atomicAdd(pu + 2, b.z); atomicAdd(pu + 3, b.w);
}

__global__ void transform_kernel(
    const float* __restrict__ agg, const float* __restrict__ deg,
    const float* __restrict__ xroot,
    const float* __restrict__ Wl, const float* __restrict__ bl,
    const float* __restrict__ Wr,
    float* __restrict__ out, int N)
{
    __shared__ float sWl[64 * 64];
    __shared__ float sWr[64 * 64];
    __shared__ float sb[64];
    __shared__ float sAgg[4][64];
    __shared__ float sX[4][64];

    const int t = threadIdx.x;
    for (int i = t; i < 64 * 64; i += 256) {
        sWl[i] = Wl[i];
        sWr[i] = Wr[i];
    }
    if (t < 64) sb[t] = bl[t];
    __syncthreads();

    const int rg = t >> 6;
    const int h  = t & 63;

    for (long long r0 = (long long)blockIdx.x * 4; r0 < N; r0 += (long long)gridDim.x * 4) {
        const long long r = r0 + rg;
        if (r < N) {
            float inv = 1.0f / fmaxf(deg[r], 1.0f);
            sAgg[rg][h] = agg[(r << 6) + h] * inv;
            sX[rg][h]   = xroot[(r << 6) + h];
        }
        __syncthreads();
        if (r < N) {
            float acc = sb[h];
            #pragma unroll
            for (int d = 0; d < 64; ++d) {
                acc += sAgg[rg][d] * sWl[d * 64 + h] + sX[rg][d] * sWr[d * 64 + h];
            }
            out[(r << 6) + h] = fmaxf(acc, 0.0f);
        }
        __syncthreads();
    }
}

extern "C" void kernel_launch(void* const* d_in, const int* in_sizes, int n_in,
                              void* d_out, int out_size, void* d_ws, size_t ws_size,
                              hipStream_t stream)
{
    const float* xu    = (const float*)d_in[0];
    const float* xr    = (const float*)d_in[1];
    const int*   src   = (const int*)  d_in[2];
    const int*   dst   = (const int*)  d_in[3];
    const float* Wl_ur = (const float*)d_in[4];
    const float* bl_ur = (const float*)d_in[5];
    const float* Wr_ur = (const float*)d_in[6];
    const float* Wl_ru = (const float*)d_in[7];
    const float* bl_ru = (const float*)d_in[8];
    const float* Wr_ru = (const float*)d_in[9];

    const int Nu = in_sizes[0] / 64;
    const int Nr = in_sizes[1] / 64;
    const int nE = in_sizes[2];
    const int NN = Nr + Nu;
    const int B  = (NN + 63) / 64;              // 64-node buckets

    float* out   = (float*)d_out;
    float* agg_r = out;                        // [Nr,64]
    float* agg_u = out + (long long)Nr * 64;   // [Nu,64]

    // ---- workspace layout (ints) ----
    int* cnt     = (int*)d_ws;                  // [NN]
    int* off     = cnt + NN;                    // [NN+1]
    int* partial = off + NN + 1;                // [256]
    int* bcur    = partial + 256;               // [B]
    int* nbr     = bcur + B;                    // [2E]
    int* entry   = nbr + 2ull * nE;             // [2E] (binned path only)
    const size_t needBin = ((size_t)NN + NN + 1 + 256 + B + 4ull * nE) * sizeof(int);
    const size_t needCsr = ((size_t)NN + NN + 1 + 256 + B + 2ull * nE) * sizeof(int);
    const bool packOk = (Nu < (1 << 18)) && (Nr < (1 << 18));

    if (ws_size >= needCsr) {
        // ---------------- CSR path ----------------
        hipMemsetAsync(cnt, 0, (size_t)NN * sizeof(int), stream);

        count_kernel<<<(nE + 255) / 256, 256, 0, stream>>>(src, dst, cnt, Nr, nE);

        const int nScanBlocks = (NN + SCAN_BS - 1) / SCAN_BS;   // <= 256
        scan_block_kernel<<<nScanBlocks, 256, 0, stream>>>(cnt, off, partial, NN);
        scan_partials_kernel<<<1, 256, 0, stream>>>(partial, nScanBlocks);
        scan_addback_kernel<<<(NN + 255) / 256, 256, 0, stream>>>(off, partial, NN, 2 * nE);

        const int nChunks = (nE + EPB - 1) / EPB;
        if (ws_size >= needBin && packOk) {
            // binned two-phase build (temporally dense writes)
            bcur_init_kernel<<<(B + 255) / 256, 256, 0, stream>>>(off, bcur, B, NN);
            bin_kernel<<<nChunks * 8, 256, 0, stream>>>(src, dst, bcur, entry, Nr, nE);
            fine_kernel<<<B, 256, 0, stream>>>(entry, off, cnt, nbr, NN);
        } else {
            // round-5 partitioned scatter (plain stores)
            const float invR = 8.0f / (float)Nr;
            const float invU = 8.0f / (float)Nu;
            scatter_part_kernel<<<nChunks * 8, 256, 0, stream>>>(
                src, dst, off, cnt, nbr, Nr, nE, invR, invU);
        }

        // merged gather (mean fused; writes every output row)
        {
            const long long tg = (long long)NN * 16;
            gather_mean_all_kernel<<<(int)((tg + 255) / 256), 256, 0, stream>>>(
                xu, xr, off, nbr, out, Nr, NN);
        }

        transform_v4_kernel<<<1024, 256, 0, stream>>>(
            agg_r, xr, Wl_ur, bl_ur, Wr_ur, agg_r, Nr);
        transform_v4_kernel<<<1024, 256, 0, stream>>>(
            agg_u, xu, Wl_ru, bl_ru, Wr_ru, agg_u, Nu);
    } else {
        // ---------------- fallback: atomic path ----------------
        float* deg_r = (float*)d_ws;
        float* deg_u = deg_r + Nr;
        hipMemsetAsync(d_out, 0, (size_t)out_size * sizeof(float), stream);
        hipMemsetAsync(d_ws, 0, (size_t)NN * sizeof(float), stream);

        const long long total = (long long)nE * 16;
        edge_scatter_kernel<<<(int)((total + 255) / 256), 256, 0, stream>>>(
            xu, xr, src, dst, agg_r, agg_u, deg_r, deg_u, nE);

        transform_kernel<<<2048, 256, 0, stream>>>(
            agg_r, deg_r, xr, Wl_ur, bl_ur, Wr_ur, agg_r, Nr);
        transform_kernel<<<2048, 256, 0, stream>>>(
            agg_u, deg_u, xu, Wl_ru, bl_ru, Wr_ru, agg_u, Nu);
    }
}

// Round 8
// 697.121 us; speedup vs baseline: 1.8561x; 1.8561x over previous
//
#include <hip/hip_runtime.h>

// HeteroGNN forward (SAGE mean-aggr, two relations), MI355X.
//
// Round 8: best-known composition (never benched together):
//  - single-pass count (round 6)
//  - hierarchical scan (round 2)
//  - scatter_part: slot-precomputed PLAIN-STORE scatter, 8-way node
//    partition (round 5; 175us @1.84TB/s). Negative results: f32 atomic
//    scatter (4.2GB), atomicExch (serializes), per-bucket cursor binning
//    (serializes on ~4K hot cursor words, 749us).
//  - merged one-launch gather over combined node space (round 7)
//  - transform_v4: W in 128 named VGPRs + readlane broadcast (round 6)

#define EPB 16384   // edges per chunk in partitioned scatter

// ---------------------------------------------------------------------------
// Phase A: single-pass count
// ---------------------------------------------------------------------------
__global__ void count_kernel(const int* __restrict__ src, const int* __restrict__ dst,
                             int* __restrict__ cnt, int Nr, int nE)
{
    int e = blockIdx.x * blockDim.x + threadIdx.x;
    if (e >= nE) return;
    atomicAdd(&cnt[dst[e]], 1);
    atomicAdd(&cnt[Nr + src[e]], 1);
}

#define SCAN_BS 2048   // elements per block in scan (256 thr x 8)

__global__ void scan_block_kernel(const int* __restrict__ cnt, int* __restrict__ off,
                                  int* __restrict__ partial, int N)
{
    __shared__ int sdata[256];
    const int t = threadIdx.x;
    const long long base = (long long)blockIdx.x * SCAN_BS + (long long)t * 8;
    int v[8];
    int s = 0;
    #pragma unroll
    for (int k = 0; k < 8; ++k) {
        long long i = base + k;
        v[k] = (i < N) ? cnt[i] : 0;
        s += v[k];
    }
    sdata[t] = s;
    __syncthreads();
    for (int d = 1; d < 256; d <<= 1) {
        int val = (t >= d) ? sdata[t - d] : 0;
        __syncthreads();
        if (t >= d) sdata[t] += val;
        __syncthreads();
    }
    if (t == 255) partial[blockIdx.x] = sdata[255];
    int run = sdata[t] - s;   // exclusive prefix for this thread's chunk
    #pragma unroll
    for (int k = 0; k < 8; ++k) {
        long long i = base + k;
        if (i < N) off[i] = run;
        run += v[k];
    }
}

__global__ void scan_partials_kernel(int* __restrict__ partial, int nb)
{
    __shared__ int sdata[256];
    const int t = threadIdx.x;
    int v = (t < nb) ? partial[t] : 0;
    sdata[t] = v;
    __syncthreads();
    for (int d = 1; d < 256; d <<= 1) {
        int val = (t >= d) ? sdata[t - d] : 0;
        __syncthreads();
        if (t >= d) sdata[t] += val;
        __syncthreads();
    }
    if (t < nb) partial[t] = sdata[t] - v;   // exclusive
}

__global__ void scan_addback_kernel(int* __restrict__ off, const int* __restrict__ partial,
                                    int N, int total)
{
    long long i = (long long)blockIdx.x * blockDim.x + threadIdx.x;
    if (i < N) off[i] += partial[i / SCAN_BS];
    if (i == 0) off[N] = total;
}

// ---------------------------------------------------------------------------
// Phase A2: partitioned bucket scatter (plain stores, slot via atomicSub on
// the L2-resident cnt array; 8-way node partition for XCD write locality).
// ---------------------------------------------------------------------------
__global__ void scatter_part_kernel(const int* __restrict__ src, const int* __restrict__ dst,
                                    const int* __restrict__ off, int* __restrict__ cnt,
                                    int* __restrict__ nbr, int Nr, int nE,
                                    float invR, float invU)
{
    const int p  = blockIdx.x & 7;
    const int c  = blockIdx.x >> 3;
    const int e0 = c * EPB;
    const int e1 = min(e0 + EPB, nE);
    for (int e = e0 + threadIdx.x; e < e1; e += blockDim.x) {
        const int dr = dst[e];
        const int su = src[e];
        if (min(7, (int)(dr * invR)) == p) {
            int pos = off[dr] + atomicSub(&cnt[dr], 1) - 1;
            nbr[pos] = su;
        }
        if (min(7, (int)(su * invU)) == p) {
            int pos = off[Nr + su] + atomicSub(&cnt[Nr + su], 1) - 1;
            nbr[pos] = dr;
        }
    }
}

// ---------------------------------------------------------------------------
// Phase B: merged atomic-free gather + mean over the combined node space.
// g < Nr: resource node (neighbors = user ids -> gather xu);
// g >= Nr: user node (neighbors = resource ids -> gather xr).
// Output row g of d_out (agg_r then agg_u contiguous).
// ---------------------------------------------------------------------------
__device__ __forceinline__ void f4add(float4& a, const float4 v) {
    a.x += v.x; a.y += v.y; a.z += v.z; a.w += v.w;
}

__global__ void gather_mean_all_kernel(const float* __restrict__ xu,
                                       const float* __restrict__ xr,
                                       const int* __restrict__ off,
                                       const int* __restrict__ nbr,
                                       float* __restrict__ out, int Nr, int NN)
{
    const int tid  = blockIdx.x * blockDim.x + threadIdx.x;
    const int g    = tid >> 4;
    if (g >= NN) return;
    const int lane = tid & 15;
    const int c    = lane << 2;
    const float* __restrict__ x = (g < Nr) ? xu : xr;

    const int beg = off[g];
    const int end = off[g + 1];

    float4 a0 = {0,0,0,0}, a1 = {0,0,0,0}, a2 = {0,0,0,0}, a3 = {0,0,0,0};
    int j = beg;
    for (; j + 4 <= end; j += 4) {
        const int s0 = nbr[j], s1 = nbr[j+1], s2 = nbr[j+2], s3 = nbr[j+3];
        f4add(a0, *reinterpret_cast<const float4*>(x + ((long long)s0 << 6) + c));
        f4add(a1, *reinterpret_cast<const float4*>(x + ((long long)s1 << 6) + c));
        f4add(a2, *reinterpret_cast<const float4*>(x + ((long long)s2 << 6) + c));
        f4add(a3, *reinterpret_cast<const float4*>(x + ((long long)s3 << 6) + c));
    }
    for (; j < end; ++j) {
        f4add(a0, *reinterpret_cast<const float4*>(x + ((long long)nbr[j] << 6) + c));
    }
    f4add(a0, a1); f4add(a2, a3); f4add(a0, a2);

    const float inv = 1.0f / (float)max(end - beg, 1);
    float4 r; r.x = a0.x * inv; r.y = a0.y * inv; r.z = a0.z * inv; r.w = a0.w * inv;
    *reinterpret_cast<float4*>(out + ((long long)g << 6) + c) = r;
}

// ---------------------------------------------------------------------------
// Phase C (v4): lane = output feature h and row element d; W in 128 named
// float4 VGPRs; readlane broadcasts row elements as SGPR operands to v_fmac.
// In-place safe (row fully read before store; wave owns its row).
// ---------------------------------------------------------------------------
__device__ __forceinline__ float rlane(float v, int l) {
    return __int_as_float(__builtin_amdgcn_readlane(__float_as_int(v), l));
}

#define LWV(nm, W, i) \
    float4 nm; nm.x = W[(4*(i)+0)*64 + lane]; nm.y = W[(4*(i)+1)*64 + lane]; \
    nm.z = W[(4*(i)+2)*64 + lane]; nm.w = W[(4*(i)+3)*64 + lane];

#define TSTEP(i, acc) { \
    acc = fmaf(rlane(va, 4*(i)+0), wl##i.x, acc); \
    acc = fmaf(rlane(va, 4*(i)+1), wl##i.y, acc); \
    acc = fmaf(rlane(va, 4*(i)+2), wl##i.z, acc); \
    acc = fmaf(rlane(va, 4*(i)+3), wl##i.w, acc); \
    acc = fmaf(rlane(vx, 4*(i)+0), wr##i.x, acc); \
    acc = fmaf(rlane(vx, 4*(i)+1), wr##i.y, acc); \
    acc = fmaf(rlane(vx, 4*(i)+2), wr##i.z, acc); \
    acc = fmaf(rlane(vx, 4*(i)+3), wr##i.w, acc); }

__global__ __launch_bounds__(256, 3)
void transform_v4_kernel(const float* __restrict__ agg,
                         const float* __restrict__ xroot,
                         const float* __restrict__ Wl,
                         const float* __restrict__ bl,
                         const float* __restrict__ Wr,
                         float* __restrict__ out, int N)
{
    const int lane = threadIdx.x & 63;
    const int wid  = (blockIdx.x * blockDim.x + threadIdx.x) >> 6;
    const int nw   = (gridDim.x * blockDim.x) >> 6;

    LWV(wl0,  Wl, 0)  LWV(wl1,  Wl, 1)  LWV(wl2,  Wl, 2)  LWV(wl3,  Wl, 3)
    LWV(wl4,  Wl, 4)  LWV(wl5,  Wl, 5)  LWV(wl6,  Wl, 6)  LWV(wl7,  Wl, 7)
    LWV(wl8,  Wl, 8)  LWV(wl9,  Wl, 9)  LWV(wl10, Wl, 10) LWV(wl11, Wl, 11)
    LWV(wl12, Wl, 12) LWV(wl13, Wl, 13) LWV(wl14, Wl, 14) LWV(wl15, Wl, 15)
    LWV(wr0,  Wr, 0)  LWV(wr1,  Wr, 1)  LWV(wr2,  Wr, 2)  LWV(wr3,  Wr, 3)
    LWV(wr4,  Wr, 4)  LWV(wr5,  Wr, 5)  LWV(wr6,  Wr, 6)  LWV(wr7,  Wr, 7)
    LWV(wr8,  Wr, 8)  LWV(wr9,  Wr, 9)  LWV(wr10, Wr, 10) LWV(wr11, Wr, 11)
    LWV(wr12, Wr, 12) LWV(wr13, Wr, 13) LWV(wr14, Wr, 14) LWV(wr15, Wr, 15)
    const float bias = bl[lane];

    for (int r = wid; r < N; r += nw) {
        const long long base = (long long)r << 6;
        const float va = agg[base + lane];     // coalesced; lane = element d
        const float vx = xroot[base + lane];
        float acc0 = bias, acc1 = 0.f, acc2 = 0.f, acc3 = 0.f;
        TSTEP(0,  acc0) TSTEP(1,  acc1) TSTEP(2,  acc2) TSTEP(3,  acc3)
        TSTEP(4,  acc0) TSTEP(5,  acc1) TSTEP(6,  acc2) TSTEP(7,  acc3)
        TSTEP(8,  acc0) TSTEP(9,  acc1) TSTEP(10, acc2) TSTEP(11, acc3)
        TSTEP(12, acc0) TSTEP(13, acc1) TSTEP(14, acc2) TSTEP(15, acc3)
        const float acc = (acc0 + acc1) + (acc2 + acc3);
        out[base + lane] = fmaxf(acc, 0.0f);   // lane = output feature h
    }
}

// ---------------------------------------------------------------------------
// Fallback (round-1) kernels, used only if ws_size is too small for CSR.
// ---------------------------------------------------------------------------
__global__ void edge_scatter_kernel(
    const float* __restrict__ xu, const float* __restrict__ xr,
    const int* __restrict__ src, const int* __restrict__ dst,
    float* __restrict__ agg_r, float* __restrict__ agg_u,
    float* __restrict__ deg_r, float* __restrict__ deg_u,
    int nE)
{
    int tid  = blockIdx.x * blockDim.x + threadIdx.x;
    int e    = tid >> 4;
    if (e >= nE) return;
    int lane = tid & 15;
    int su = src[e];
    int dr = dst[e];
    if (lane == 0) {
        atomicAdd(&deg_r[dr], 1.0f);
        atomicAdd(&deg_u[su], 1.0f);
    }
    const float4 a = *reinterpret_cast<const float4*>(xu + ((long long)su << 6) + (lane << 2));
    const float4 b = *reinterpret_cast<const float4*>(xr + ((long long)dr << 6) + (lane << 2));
    float* pr = agg_r + ((long long)dr << 6) + (lane << 2);
    float* pu = agg_u + ((long long)su << 6) + (lane << 2);
    atomicAdd(pr + 0, a.x); atomicAdd(pr + 1, a.y);
    atomicAdd(pr + 2, a.z); atomicAdd(pr + 3, a.w);
    atomicAdd(pu + 0, b.x); atomicAdd(pu + 1, b.y);
    atomicAdd(pu + 2, b.z); atomicAdd(pu + 3, b.w);
}

__global__ void transform_kernel(
    const float* __restrict__ agg, const float* __restrict__ deg,
    const float* __restrict__ xroot,
    const float* __restrict__ Wl, const float* __restrict__ bl,
    const float* __restrict__ Wr,
    float* __restrict__ out, int N)
{
    __shared__ float sWl[64 * 64];
    __shared__ float sWr[64 * 64];
    __shared__ float sb[64];
    __shared__ float sAgg[4][64];
    __shared__ float sX[4][64];

    const int t = threadIdx.x;
    for (int i = t; i < 64 * 64; i += 256) {
        sWl[i] = Wl[i];
        sWr[i] = Wr[i];
    }
    if (t < 64) sb[t] = bl[t];
    __syncthreads();

    const int rg = t >> 6;
    const int h  = t & 63;

    for (long long r0 = (long long)blockIdx.x * 4; r0 < N; r0 += (long long)gridDim.x * 4) {
        const long long r = r0 + rg;
        if (r < N) {
            float inv = 1.0f / fmaxf(deg[r], 1.0f);
            sAgg[rg][h] = agg[(r << 6) + h] * inv;
            sX[rg][h]   = xroot[(r << 6) + h];
        }
        __syncthreads();
        if (r < N) {
            float acc = sb[h];
            #pragma unroll
            for (int d = 0; d < 64; ++d) {
                acc += sAgg[rg][d] * sWl[d * 64 + h] + sX[rg][d] * sWr[d * 64 + h];
            }
            out[(r << 6) + h] = fmaxf(acc, 0.0f);
        }
        __syncthreads();
    }
}

extern "C" void kernel_launch(void* const* d_in, const int* in_sizes, int n_in,
                              void* d_out, int out_size, void* d_ws, size_t ws_size,
                              hipStream_t stream)
{
    const float* xu    = (const float*)d_in[0];
    const float* xr    = (const float*)d_in[1];
    const int*   src   = (const int*)  d_in[2];
    const int*   dst   = (const int*)  d_in[3];
    const float* Wl_ur = (const float*)d_in[4];
    const float* bl_ur = (const float*)d_in[5];
    const float* Wr_ur = (const float*)d_in[6];
    const float* Wl_ru = (const float*)d_in[7];
    const float* bl_ru = (const float*)d_in[8];
    const float* Wr_ru = (const float*)d_in[9];

    const int Nu = in_sizes[0] / 64;
    const int Nr = in_sizes[1] / 64;
    const int nE = in_sizes[2];
    const int NN = Nr + Nu;

    float* out   = (float*)d_out;
    float* agg_r = out;                        // [Nr,64]
    float* agg_u = out + (long long)Nr * 64;   // [Nu,64]

    // ---- workspace layout (ints) ----
    int* cnt     = (int*)d_ws;                  // [NN]
    int* off     = cnt + NN;                    // [NN+1]
    int* partial = off + NN + 1;                // [256]
    int* nbr     = partial + 256;               // [2E]
    const size_t need = ((size_t)NN + (size_t)NN + 1 + 256 + 2ull * nE) * sizeof(int);

    if (ws_size >= need) {
        // ---------------- CSR path ----------------
        hipMemsetAsync(cnt, 0, (size_t)NN * sizeof(int), stream);

        count_kernel<<<(nE + 255) / 256, 256, 0, stream>>>(src, dst, cnt, Nr, nE);

        const int nScanBlocks = (NN + SCAN_BS - 1) / SCAN_BS;   // <= 256
        scan_block_kernel<<<nScanBlocks, 256, 0, stream>>>(cnt, off, partial, NN);
        scan_partials_kernel<<<1, 256, 0, stream>>>(partial, nScanBlocks);
        scan_addback_kernel<<<(NN + 255) / 256, 256, 0, stream>>>(off, partial, NN, 2 * nE);

        const float invR = 8.0f / (float)Nr;
        const float invU = 8.0f / (float)Nu;
        const int nChunks = (nE + EPB - 1) / EPB;
        scatter_part_kernel<<<nChunks * 8, 256, 0, stream>>>(
            src, dst, off, cnt, nbr, Nr, nE, invR, invU);

        // merged gather (mean fused; writes every output row)
        {
            const long long tg = (long long)NN * 16;
            gather_mean_all_kernel<<<(int)((tg + 255) / 256), 256, 0, stream>>>(
                xu, xr, off, nbr, out, Nr, NN);
        }

        transform_v4_kernel<<<1024, 256, 0, stream>>>(
            agg_r, xr, Wl_ur, bl_ur, Wr_ur, agg_r, Nr);
        transform_v4_kernel<<<1024, 256, 0, stream>>>(
            agg_u, xu, Wl_ru, bl_ru, Wr_ru, agg_u, Nu);
    } else {
        // ---------------- fallback: atomic path ----------------
        float* deg_r = (float*)d_ws;
        float* deg_u = deg_r + Nr;
        hipMemsetAsync(d_out, 0, (size_t)out_size * sizeof(float), stream);
        hipMemsetAsync(d_ws, 0, (size_t)NN * sizeof(float), stream);

        const long long total = (long long)nE * 16;
        edge_scatter_kernel<<<(int)((total + 255) / 256), 256, 0, stream>>>(
            xu, xr, src, dst, agg_r, agg_u, deg_r, deg_u, nE);

        transform_kernel<<<2048, 256, 0, stream>>>(
            agg_r, deg_r, xr, Wl_ur, bl_ur, Wr_ur, agg_r, Nr);
        transform_kernel<<<2048, 256, 0, stream>>>(
            agg_u, deg_u, xu, Wl_ru, bl_ru, Wr_ru, agg_u, Nu);
    }
}